// Round 8
// baseline (432.167 us; speedup 1.0000x reference)
//
#include <hip/hip_runtime.h>

// ---------------------------------------------------------------------------
// GAT encoder: x --GATConv(2 heads,128)--> ELU --> {GATConv mu, GATConv ls}
// N=50000, E=800000 (+self loops). fp32 in/out. Edges int32 w/ int64 detect.
// Round 15:
//  * Layer-1 aggregate-before-transform: agg is linear, so gather x rows
//    (256B/edge fp16) instead of h1 rows (512B) -> halves agg1 bytes at the
//    measured ~3.7TB/s random-gather wall (R7-R14: time insensitive to
//    instrs/VALU, only bytes can win). Dual-head accumulators share one
//    gather; x1 = ELU(agg@W1+b) via head-split-A MFMA GEMM.
//  * Alpha logits via v-vectors: as = x.(W1^T a_src) etc. (k_vdots1/2,
//    k_cvt_asad) -- removes fp16-h rounding from logits; gemm2 epilogue-free;
//    gemm-x1 epilogue computes mu/ls alphas from ELU'd x1 with v2 vectors.
//  * agg2 (mu/ls) reverted to R12 k_agg4 half-split shape (best: 63.6us;
//    R14 merge regressed to 68 w/ occupancy 35%).
// ---------------------------------------------------------------------------

typedef unsigned short u16;
typedef unsigned int u32;
typedef _Float16 f16;
typedef f16 f16x8 __attribute__((ext_vector_type(8)));
typedef float f32x4v __attribute__((ext_vector_type(4)));

__device__ __forceinline__ u16 f2h(float f) {
    union { f16 h; u16 u; } t;
    t.h = (f16)f;
    return t.u;
}
__device__ __forceinline__ float4 loadh4(const u16* __restrict__ p, size_t i) {
    union { uint2 u; f16 h[4]; } t;
    t.u = *(const uint2*)(p + i);
    return make_float4((float)t.h[0], (float)t.h[1], (float)t.h[2], (float)t.h[3]);
}
__device__ __forceinline__ void store4(float* __restrict__ p, size_t i, float4 v) {
    *(float4*)(p + i) = v;
}
__device__ __forceinline__ void store4h(u16* __restrict__ p, size_t i, float4 v) {
    union { uint2 u; f16 h[4]; } t;
    t.h[0] = (f16)v.x; t.h[1] = (f16)v.y; t.h[2] = (f16)v.z; t.h[3] = (f16)v.w;
    *(uint2*)(p + i) = t.u;
}

// ---------------- edge normalize (+int64 detect, +degree count) --------------
__global__ __launch_bounds__(256) void k_extract(const u32* __restrict__ ebuf, int E,
                                                 int* __restrict__ se,
                                                 int* __restrict__ de,
                                                 int* __restrict__ deg) {
    __shared__ int nz;
    if (threadIdx.x == 0) nz = 0;
    __syncthreads();
    if (ebuf[2 * threadIdx.x + 1] != 0u) atomicAdd(&nz, 1);
    __syncthreads();
    const bool i64 = (nz == 0);
    int e = blockIdx.x * 256 + threadIdx.x;
    if (e >= E) return;
    int s, d;
    if (i64) {
        s = (int)ebuf[2 * (size_t)e];
        d = (int)ebuf[2 * ((size_t)E + (size_t)e)];
    } else {
        s = (int)ebuf[e];
        d = (int)ebuf[(size_t)E + (size_t)e];
    }
    se[e] = s;
    de[e] = d;
    atomicAdd(&deg[d], 1);
}

// ---------------- CSR build ----------------
__global__ __launch_bounds__(256) void k_scan_a(const int* __restrict__ deg, int n,
                                                int* __restrict__ bsum) {
    __shared__ int s[256];
    int i = blockIdx.x * 256 + threadIdx.x;
    s[threadIdx.x] = (i < n) ? deg[i] : 0;
    __syncthreads();
    for (int st = 128; st > 0; st >>= 1) {
        if (threadIdx.x < st) s[threadIdx.x] += s[threadIdx.x + st];
        __syncthreads();
    }
    if (threadIdx.x == 0) bsum[blockIdx.x] = s[0];
}

__global__ __launch_bounds__(256) void k_scan_b(int* __restrict__ bsum, int nb) {
    __shared__ int s[256];
    int t = threadIdx.x;
    int v = (t < nb) ? bsum[t] : 0;
    s[t] = v;
    __syncthreads();
    for (int off = 1; off < 256; off <<= 1) {
        int add = (t >= off) ? s[t - off] : 0;
        __syncthreads();
        s[t] += add;
        __syncthreads();
    }
    if (t < nb) bsum[t] = s[t] - v;  // exclusive
}

__global__ __launch_bounds__(256) void k_scan_c(const int* __restrict__ deg, int n,
                                                const int* __restrict__ bsum,
                                                int* __restrict__ rowptr,
                                                int* __restrict__ cursor, int E) {
    __shared__ int s[256];
    int t = threadIdx.x;
    int i = blockIdx.x * 256 + t;
    int v = (i < n) ? deg[i] : 0;
    s[t] = v;
    __syncthreads();
    for (int off = 1; off < 256; off <<= 1) {
        int add = (t >= off) ? s[t - off] : 0;
        __syncthreads();
        s[t] += add;
        __syncthreads();
    }
    if (i < n) {
        int ex = bsum[blockIdx.x] + s[t] - v;
        rowptr[i] = ex;
        cursor[i] = ex;
    }
    if (i == 0) rowptr[n] = E;
}

__global__ __launch_bounds__(256) void k_fill(const int* __restrict__ src,
                                              const int* __restrict__ dst, int E,
                                              int* __restrict__ cursor,
                                              int* __restrict__ csr_src,
                                              int* __restrict__ csr_dst) {
    int e = blockIdx.x * 256 + threadIdx.x;
    if (e < 8) csr_src[E + e] = 0;  // pad
    if (e < E) {
        int d = dst[e];
        int slot = atomicAdd(&cursor[d], 1);
        csr_src[slot] = src[e];
        csr_dst[slot] = d;
    }
}

// Wt[c][k] = W[k][c] as fp16.  split==256: single W (row stride 256);
// split==128: c<128 from Wl, else Wr (row stride 128).
__global__ __launch_bounds__(256) void k_tw(const float* __restrict__ Wl,
                                            const float* __restrict__ Wr, int split,
                                            int K, u16* __restrict__ Wt) {
    int idx = blockIdx.x * 256 + threadIdx.x;
    if (idx >= 256 * K) return;
    int c = idx / K, k = idx - c * K;
    float v;
    if (split == 256)
        v = Wl[(size_t)k * 256 + c];
    else
        v = (c < 128) ? Wl[(size_t)k * 128 + c] : Wr[(size_t)k * 128 + (c - 128)];
    Wt[idx] = f2h(v);
}

// ---------------- alpha v-vectors ------------------------------------------
// v1[4][128]: {src_h0, src_h1, dst_h0, dst_h1}; v1[q][c] = sum_j W1[c][hd*128+j]*a[hd*128+j]
__global__ void k_vdots1(const float* __restrict__ W1,
                         const float* __restrict__ a_src,
                         const float* __restrict__ a_dst,
                         float* __restrict__ v1) {
    int c = threadIdx.x;  // 128
    if (c >= 128) return;
    const float* wr = W1 + (size_t)c * 256;
    float s0 = 0, s1 = 0, d0 = 0, d1 = 0;
    for (int j = 0; j < 128; j++) {
        float w0 = wr[j], w1 = wr[128 + j];
        s0 += w0 * a_src[j];
        s1 += w1 * a_src[128 + j];
        d0 += w0 * a_dst[j];
        d1 += w1 * a_dst[128 + j];
    }
    v1[c] = s0;
    v1[128 + c] = s1;
    v1[256 + c] = d0;
    v1[384 + c] = d1;
}

// v2s/v2d [4][256], slots {mu_h0, mu_h1, ls_h0, ls_h1}; over x1 channels j.
__global__ void k_vdots2(const float* __restrict__ Wmu, const float* __restrict__ Wls,
                         const float* __restrict__ smu, const float* __restrict__ dmu,
                         const float* __restrict__ sls, const float* __restrict__ dls,
                         float* __restrict__ v2s, float* __restrict__ v2d) {
    int j = threadIdx.x;  // 256
    const float* wm = Wmu + (size_t)j * 128;
    const float* wl = Wls + (size_t)j * 128;
    float s0 = 0, s1 = 0, s2 = 0, s3 = 0, d0 = 0, d1 = 0, d2 = 0, d3 = 0;
    for (int k = 0; k < 64; k++) {
        float m0 = wm[k], m1 = wm[64 + k], l0 = wl[k], l1 = wl[64 + k];
        s0 += m0 * smu[k];
        s1 += m1 * smu[64 + k];
        s2 += l0 * sls[k];
        s3 += l1 * sls[64 + k];
        d0 += m0 * dmu[k];
        d1 += m1 * dmu[64 + k];
        d2 += l0 * dls[k];
        d3 += l1 * dls[64 + k];
    }
    v2s[j] = s0; v2s[256 + j] = s1; v2s[512 + j] = s2; v2s[768 + j] = s3;
    v2d[j] = d0; v2d[256 + j] = d1; v2d[512 + j] = d2; v2d[768 + j] = d3;
}

// ---------------- x -> fp16 + layer-1 as/ad (wave per node) ------------------
__global__ __launch_bounds__(256) void k_cvt_asad(const float* __restrict__ x,
                                                  const float* __restrict__ v1,
                                                  u16* __restrict__ xh,
                                                  float* __restrict__ as,
                                                  float* __restrict__ ad, int n) {
    int wid = blockIdx.x * 4 + (threadIdx.x >> 6);
    if (wid >= n) return;
    int lane = threadIdx.x & 63;
    float2 xv = *(const float2*)(x + (size_t)wid * 128 + lane * 2);
    union { u32 u; f16 h[2]; } t;
    t.h[0] = (f16)xv.x;
    t.h[1] = (f16)xv.y;
    *(u32*)(xh + (size_t)wid * 128 + lane * 2) = t.u;
    int c = lane * 2;
    float s0 = xv.x * v1[c] + xv.y * v1[c + 1];
    float s1 = xv.x * v1[128 + c] + xv.y * v1[128 + c + 1];
    float d0 = xv.x * v1[256 + c] + xv.y * v1[256 + c + 1];
    float d1 = xv.x * v1[384 + c] + xv.y * v1[384 + c + 1];
#pragma unroll
    for (int m = 1; m <= 32; m <<= 1) {
        s0 += __shfl_xor(s0, m, 64);
        s1 += __shfl_xor(s1, m, 64);
        d0 += __shfl_xor(d0, m, 64);
        d1 += __shfl_xor(d1, m, 64);
    }
    if (lane == 0) {
        as[(size_t)wid * 2] = s0;
        as[(size_t)wid * 2 + 1] = s1;
        ad[(size_t)wid * 2] = d0;
        ad[(size_t)wid * 2 + 1] = d1;
    }
}

// ---------------- edge-weight precompute (CSR order, per-slot planes) --------
template <int NS>
__global__ __launch_bounds__(256) void k_w(const int* __restrict__ csr_src,
                                           const int* __restrict__ csr_dst,
                                           const float* __restrict__ as,
                                           const float* __restrict__ ad,
                                           float* __restrict__ wp, int E, int Ep) {
    int i = blockIdx.x * 256 + threadIdx.x;
    if (i >= E) return;
    int s = csr_src[i], d = csr_dst[i];
    if (NS == 2) {
        float2 a = *(const float2*)(as + (size_t)s * 2);
        float2 b = *(const float2*)(ad + (size_t)d * 2);
        float e0 = a.x + b.x, e1 = a.y + b.y;
        e0 = fmaxf(e0, 0.2f * e0);
        e1 = fmaxf(e1, 0.2f * e1);
        wp[i] = __expf(e0);
        wp[(size_t)Ep + i] = __expf(e1);
    } else {
        float4 a = *(const float4*)(as + (size_t)s * 4);
        float4 b = *(const float4*)(ad + (size_t)d * 4);
        float e0 = a.x + b.x, e1 = a.y + b.y, e2 = a.z + b.z, e3 = a.w + b.w;
        e0 = fmaxf(e0, 0.2f * e0);
        e1 = fmaxf(e1, 0.2f * e1);
        e2 = fmaxf(e2, 0.2f * e2);
        e3 = fmaxf(e3, 0.2f * e3);
        wp[i] = __expf(e0);
        wp[(size_t)Ep + i] = __expf(e1);
        wp[2 * (size_t)Ep + i] = __expf(e2);
        wp[3 * (size_t)Ep + i] = __expf(e3);
    }
}

// ---------------- layer-1 aggregation in x-space (256B/edge) -----------------
// 32-lane half-wave per node, lane owns 4 of 128 cols (8B gathers). ONE gather
// per edge feeds BOTH heads' accumulators (weights from wp planes 0/1).
// Output agg[n,256] fp16: cols 0-127 = head0 aggregate, 128-255 = head1.
__global__ __launch_bounds__(256) void k_agg1(
    const u16* __restrict__ xh, const int* __restrict__ rowptr,
    const int* __restrict__ csr_src, const float* __restrict__ wp,
    const float* __restrict__ as, const float* __restrict__ ad,
    u16* __restrict__ aggout, int n, int Ep) {
    const int lane = threadIdx.x & 63;
    const int sub = lane >> 5;
    const int sl = lane & 31;
    const int wid0 = blockIdx.x * 8 + (threadIdx.x >> 6) * 2 + sub;
    const bool ok = wid0 < n;
    const int wid = ok ? wid0 : (n - 1);
    const int col = sl * 4;
    const float* __restrict__ wp0 = wp;
    const float* __restrict__ wp1 = wp + Ep;

    float e0 = as[(size_t)wid * 2] + ad[(size_t)wid * 2];
    float e1 = as[(size_t)wid * 2 + 1] + ad[(size_t)wid * 2 + 1];
    e0 = fmaxf(e0, 0.2f * e0);
    e1 = fmaxf(e1, 0.2f * e1);
    float w0s = __expf(e0), w1s = __expf(e1);
    float den0 = w0s, den1 = w1s;
    float4 hv = loadh4(xh, (size_t)wid * 128 + col);
    float a0x = w0s * hv.x, a0y = w0s * hv.y, a0z = w0s * hv.z, a0w = w0s * hv.w;
    float b0x = w1s * hv.x, b0y = w1s * hv.y, b0z = w1s * hv.z, b0w = w1s * hv.w;

    int rb = 0, re = 0;
    if (ok) { rb = rowptr[wid0]; re = rowptr[wid0 + 1]; }
    int p = rb;
    for (; p + 8 <= re; p += 8) {
        int4 sA = *(const int4*)(csr_src + p);
        int4 sB = *(const int4*)(csr_src + p + 4);
        float4 uA = *(const float4*)(wp0 + p);
        float4 uB = *(const float4*)(wp0 + p + 4);
        float4 vA = *(const float4*)(wp1 + p);
        float4 vB = *(const float4*)(wp1 + p + 4);
        float4 h0 = loadh4(xh, (size_t)sA.x * 128 + col);
        float4 h1 = loadh4(xh, (size_t)sA.y * 128 + col);
        float4 h2 = loadh4(xh, (size_t)sA.z * 128 + col);
        float4 h3 = loadh4(xh, (size_t)sA.w * 128 + col);
        float4 h4 = loadh4(xh, (size_t)sB.x * 128 + col);
        float4 h5 = loadh4(xh, (size_t)sB.y * 128 + col);
        float4 h6 = loadh4(xh, (size_t)sB.z * 128 + col);
        float4 h7 = loadh4(xh, (size_t)sB.w * 128 + col);
        den0 += (uA.x + uA.y + uA.z + uA.w) + (uB.x + uB.y + uB.z + uB.w);
        den1 += (vA.x + vA.y + vA.z + vA.w) + (vB.x + vB.y + vB.z + vB.w);
        a0x += uA.x * h0.x + uA.y * h1.x + uA.z * h2.x + uA.w * h3.x +
               uB.x * h4.x + uB.y * h5.x + uB.z * h6.x + uB.w * h7.x;
        a0y += uA.x * h0.y + uA.y * h1.y + uA.z * h2.y + uA.w * h3.y +
               uB.x * h4.y + uB.y * h5.y + uB.z * h6.y + uB.w * h7.y;
        a0z += uA.x * h0.z + uA.y * h1.z + uA.z * h2.z + uA.w * h3.z +
               uB.x * h4.z + uB.y * h5.z + uB.z * h6.z + uB.w * h7.z;
        a0w += uA.x * h0.w + uA.y * h1.w + uA.z * h2.w + uA.w * h3.w +
               uB.x * h4.w + uB.y * h5.w + uB.z * h6.w + uB.w * h7.w;
        b0x += vA.x * h0.x + vA.y * h1.x + vA.z * h2.x + vA.w * h3.x +
               vB.x * h4.x + vB.y * h5.x + vB.z * h6.x + vB.w * h7.x;
        b0y += vA.x * h0.y + vA.y * h1.y + vA.z * h2.y + vA.w * h3.y +
               vB.x * h4.y + vB.y * h5.y + vB.z * h6.y + vB.w * h7.y;
        b0z += vA.x * h0.z + vA.y * h1.z + vA.z * h2.z + vA.w * h3.z +
               vB.x * h4.z + vB.y * h5.z + vB.z * h6.z + vB.w * h7.z;
        b0w += vA.x * h0.w + vA.y * h1.w + vA.z * h2.w + vA.w * h3.w +
               vB.x * h4.w + vB.y * h5.w + vB.z * h6.w + vB.w * h7.w;
    }
    for (; p + 4 <= re; p += 4) {
        int4 sA = *(const int4*)(csr_src + p);
        float4 uA = *(const float4*)(wp0 + p);
        float4 vA = *(const float4*)(wp1 + p);
        float4 h0 = loadh4(xh, (size_t)sA.x * 128 + col);
        float4 h1 = loadh4(xh, (size_t)sA.y * 128 + col);
        float4 h2 = loadh4(xh, (size_t)sA.z * 128 + col);
        float4 h3 = loadh4(xh, (size_t)sA.w * 128 + col);
        den0 += (uA.x + uA.y) + (uA.z + uA.w);
        den1 += (vA.x + vA.y) + (vA.z + vA.w);
        a0x += uA.x * h0.x + uA.y * h1.x + uA.z * h2.x + uA.w * h3.x;
        a0y += uA.x * h0.y + uA.y * h1.y + uA.z * h2.y + uA.w * h3.y;
        a0z += uA.x * h0.z + uA.y * h1.z + uA.z * h2.z + uA.w * h3.z;
        a0w += uA.x * h0.w + uA.y * h1.w + uA.z * h2.w + uA.w * h3.w;
        b0x += vA.x * h0.x + vA.y * h1.x + vA.z * h2.x + vA.w * h3.x;
        b0y += vA.x * h0.y + vA.y * h1.y + vA.z * h2.y + vA.w * h3.y;
        b0z += vA.x * h0.z + vA.y * h1.z + vA.z * h2.z + vA.w * h3.z;
        b0w += vA.x * h0.w + vA.y * h1.w + vA.z * h2.w + vA.w * h3.w;
    }
    for (; p < re; ++p) {
        int s = csr_src[p];
        float u = wp0[p], v = wp1[p];
        float4 hh = loadh4(xh, (size_t)s * 128 + col);
        den0 += u;
        den1 += v;
        a0x += u * hh.x; a0y += u * hh.y; a0z += u * hh.z; a0w += u * hh.w;
        b0x += v * hh.x; b0y += v * hh.y; b0z += v * hh.z; b0w += v * hh.w;
    }
    if (!ok) return;
    float i0 = 1.0f / (den0 + 1e-16f);
    float i1 = 1.0f / (den1 + 1e-16f);
    store4h(aggout, (size_t)wid0 * 256 + col,
            make_float4(a0x * i0, a0y * i0, a0z * i0, a0w * i0));
    store4h(aggout, (size_t)wid0 * 256 + 128 + col,
            make_float4(b0x * i1, b0y * i1, b0z * i1, b0w * i1));
}

// ---------------- GEMM x1 = ELU(agg@W1 + b1), head-split A, v2 alphas --------
// Ag[M,256]: cols 0-127 = head0 agg, 128-255 = head1. Wt = W1^T [256][128].
// Output cols 0-127 use A-h0, 128-255 use A-h1. Epilogue: bias+ELU -> x1h
// fp16; as/ad (NS=4) = ELU'd row dot v2s/v2d slots.
__global__ __launch_bounds__(256) void k_gemm_x1(
    const u16* __restrict__ Ag, const u16* __restrict__ Wt, u16* __restrict__ x1out,
    float* __restrict__ as_out, float* __restrict__ ad_out,
    const float* __restrict__ b1, const float* __restrict__ v2s,
    const float* __restrict__ v2d, int M) {
    __shared__ u16 Bs[256 * 40];  // 20KB
    const int tid = threadIdx.x;
    const int wave = tid >> 6;
    const int lane = tid & 63;
    const int li = lane & 15;
    const int quad = lane >> 4;
    const int r0 = blockIdx.x * 128 + wave * 32;
    int ar0 = r0 + li;
    int ar1 = r0 + 16 + li;
    if (ar0 >= M) ar0 = M - 1;
    if (ar1 >= M) ar1 = M - 1;
    const u16* a00p = Ag + (size_t)ar0 * 256 + quad * 8;        // row0 head0
    const u16* a01p = Ag + (size_t)ar0 * 256 + 128 + quad * 8;  // row0 head1
    const u16* a10p = Ag + (size_t)ar1 * 256 + quad * 8;
    const u16* a11p = Ag + (size_t)ar1 * 256 + 128 + quad * 8;

    f32x4v acc0[16], acc1[16];
#pragma unroll
    for (int ct = 0; ct < 16; ct++) {
        acc0[ct] = (f32x4v)(0.f);
        acc1[ct] = (f32x4v)(0.f);
    }

    const u16* wrow = Wt + (size_t)tid * 128;
    u16* dstp = Bs + tid * 40;
    uint4 sv0 = ((const uint4*)wrow)[0];
    uint4 sv1 = ((const uint4*)(wrow + 8))[0];
    uint4 sv2 = ((const uint4*)(wrow + 16))[0];
    uint4 sv3 = ((const uint4*)(wrow + 24))[0];
    uint4 p00 = *(const uint4*)a00p;
    uint4 p01 = *(const uint4*)a01p;
    uint4 p10 = *(const uint4*)a10p;
    uint4 p11 = *(const uint4*)a11p;

    for (int t = 0; t < 128; t += 32) {
        asm volatile("s_waitcnt lgkmcnt(0)" ::: "memory");
        __builtin_amdgcn_s_barrier();
        ((uint4*)dstp)[0] = sv0;
        ((uint4*)(dstp + 8))[0] = sv1;
        ((uint4*)(dstp + 16))[0] = sv2;
        ((uint4*)(dstp + 24))[0] = sv3;
        union { uint4 u; f16x8 h; } uh;
        f16x8 a00, a01, a10, a11;
        uh.u = p00; a00 = uh.h;
        uh.u = p01; a01 = uh.h;
        uh.u = p10; a10 = uh.h;
        uh.u = p11; a11 = uh.h;
        if (t + 32 < 128) {
            const u16* s2 = wrow + t + 32;
            sv0 = ((const uint4*)s2)[0];
            sv1 = ((const uint4*)(s2 + 8))[0];
            sv2 = ((const uint4*)(s2 + 16))[0];
            sv3 = ((const uint4*)(s2 + 24))[0];
            p00 = *(const uint4*)(a00p + t + 32);
            p01 = *(const uint4*)(a01p + t + 32);
            p10 = *(const uint4*)(a10p + t + 32);
            p11 = *(const uint4*)(a11p + t + 32);
        }
        asm volatile("s_waitcnt lgkmcnt(0)" ::: "memory");
        __builtin_amdgcn_s_barrier();
#pragma unroll
        for (int ct = 0; ct < 16; ct++) {
            f16x8 b = *(const f16x8*)(Bs + (ct * 16 + li) * 40 + quad * 8);
            if (ct < 8) {
                acc0[ct] = __builtin_amdgcn_mfma_f32_16x16x32_f16(a00, b, acc0[ct], 0, 0, 0);
                acc1[ct] = __builtin_amdgcn_mfma_f32_16x16x32_f16(a10, b, acc1[ct], 0, 0, 0);
            } else {
                acc0[ct] = __builtin_amdgcn_mfma_f32_16x16x32_f16(a01, b, acc0[ct], 0, 0, 0);
                acc1[ct] = __builtin_amdgcn_mfma_f32_16x16x32_f16(a11, b, acc1[ct], 0, 0, 0);
            }
        }
    }

    float bval[16];
#pragma unroll
    for (int ct = 0; ct < 16; ct++) bval[ct] = b1[ct * 16 + li];

    auto epilogue = [&](f32x4v(&acc)[16], int rbase) {
        // bias + ELU in place, store x1 fp16
#pragma unroll
        for (int ct = 0; ct < 16; ct++) {
#pragma unroll
            for (int reg = 0; reg < 4; reg++) {
                float v = acc[ct][reg] + bval[ct];
                acc[ct][reg] = v > 0.f ? v : expm1f(v);
            }
        }
#pragma unroll
        for (int reg = 0; reg < 4; reg++) {
            int grow = rbase + quad * 4 + reg;
            if (grow < M) {
                u16* orow = x1out + (size_t)grow * 256 + li;
#pragma unroll
                for (int ct = 0; ct < 16; ct++) orow[ct * 16] = f2h(acc[ct][reg]);
            }
        }
        // alphas: s[sl] = x1 . v2s[sl], d[sl] = x1 . v2d[sl]
#pragma unroll
        for (int sl = 0; sl < 4; sl++) {
            float aw[16], dw[16];
#pragma unroll
            for (int ct = 0; ct < 16; ct++) {
                aw[ct] = v2s[sl * 256 + ct * 16 + li];
                dw[ct] = v2d[sl * 256 + ct * 16 + li];
            }
#pragma unroll
            for (int reg = 0; reg < 4; reg++) {
                float s = 0.f, d = 0.f;
#pragma unroll
                for (int ct = 0; ct < 16; ct++) {
                    s += acc[ct][reg] * aw[ct];
                    d += acc[ct][reg] * dw[ct];
                }
#pragma unroll
                for (int m = 1; m <= 8; m <<= 1) {
                    s += __shfl_xor(s, m, 64);
                    d += __shfl_xor(d, m, 64);
                }
                int grow = rbase + quad * 4 + reg;
                if (li == 0 && grow < M) {
                    as_out[(size_t)grow * 4 + sl] = s;
                    ad_out[(size_t)grow * 4 + sl] = d;
                }
            }
        }
    };
    epilogue(acc0, r0);
    epilogue(acc1, r0 + 16);
}

// ---------------- GEMM h2 = x1@[Wmu|Wls] (pure, no epilogue) -----------------
__global__ __launch_bounds__(256) void k_gemm_h(const u16* __restrict__ Ah,
                                                const u16* __restrict__ Wt,
                                                u16* __restrict__ out, int M) {
    __shared__ u16 Bs[256 * 40];
    const int tid = threadIdx.x;
    const int wave = tid >> 6;
    const int lane = tid & 63;
    const int li = lane & 15;
    const int quad = lane >> 4;
    const int r0 = blockIdx.x * 128 + wave * 32;
    int ar0 = r0 + li;
    int ar1 = r0 + 16 + li;
    if (ar0 >= M) ar0 = M - 1;
    if (ar1 >= M) ar1 = M - 1;
    const u16* a0p = Ah + (size_t)ar0 * 256 + quad * 8;
    const u16* a1p = Ah + (size_t)ar1 * 256 + quad * 8;

    f32x4v acc0[16], acc1[16];
#pragma unroll
    for (int ct = 0; ct < 16; ct++) {
        acc0[ct] = (f32x4v)(0.f);
        acc1[ct] = (f32x4v)(0.f);
    }

    const u16* wrow = Wt + (size_t)tid * 256;
    u16* dstp = Bs + tid * 40;
    uint4 sv0 = ((const uint4*)wrow)[0];
    uint4 sv1 = ((const uint4*)(wrow + 8))[0];
    uint4 sv2 = ((const uint4*)(wrow + 16))[0];
    uint4 sv3 = ((const uint4*)(wrow + 24))[0];
    uint4 p0 = *(const uint4*)a0p;
    uint4 p1 = *(const uint4*)a1p;

    for (int t = 0; t < 256; t += 32) {
        asm volatile("s_waitcnt lgkmcnt(0)" ::: "memory");
        __builtin_amdgcn_s_barrier();
        ((uint4*)dstp)[0] = sv0;
        ((uint4*)(dstp + 8))[0] = sv1;
        ((uint4*)(dstp + 16))[0] = sv2;
        ((uint4*)(dstp + 24))[0] = sv3;
        union { uint4 u; f16x8 h; } uh;
        f16x8 a0, a1;
        uh.u = p0; a0 = uh.h;
        uh.u = p1; a1 = uh.h;
        if (t + 32 < 256) {
            const u16* s2 = wrow + t + 32;
            sv0 = ((const uint4*)s2)[0];
            sv1 = ((const uint4*)(s2 + 8))[0];
            sv2 = ((const uint4*)(s2 + 16))[0];
            sv3 = ((const uint4*)(s2 + 24))[0];
            p0 = *(const uint4*)(a0p + t + 32);
            p1 = *(const uint4*)(a1p + t + 32);
        }
        asm volatile("s_waitcnt lgkmcnt(0)" ::: "memory");
        __builtin_amdgcn_s_barrier();
#pragma unroll
        for (int ct = 0; ct < 16; ct++) {
            f16x8 b = *(const f16x8*)(Bs + (ct * 16 + li) * 40 + quad * 8);
            acc0[ct] = __builtin_amdgcn_mfma_f32_16x16x32_f16(a0, b, acc0[ct], 0, 0, 0);
            acc1[ct] = __builtin_amdgcn_mfma_f32_16x16x32_f16(a1, b, acc1[ct], 0, 0, 0);
        }
    }
#pragma unroll
    for (int reg = 0; reg < 4; reg++) {
        int g0 = r0 + quad * 4 + reg;
        if (g0 < M) {
            u16* orow = out + (size_t)g0 * 256 + li;
#pragma unroll
            for (int ct = 0; ct < 16; ct++) orow[ct * 16] = f2h(acc0[ct][reg]);
        }
        int g1 = r0 + 16 + quad * 4 + reg;
        if (g1 < M) {
            u16* orow = out + (size_t)g1 * 256 + li;
#pragma unroll
            for (int ct = 0; ct < 16; ct++) orow[ct * 16] = f2h(acc1[ct][reg]);
        }
    }
}

// ---------------- layer 2/3 aggregation (R12 k_agg4, MODE1) ------------------
__global__ __launch_bounds__(256) void k_agg4(
    const u16* __restrict__ h, const int* __restrict__ rowptr,
    const int* __restrict__ csr_src, const float* __restrict__ wp,
    const float* __restrict__ as, const float* __restrict__ ad,
    const float* __restrict__ b_lo, const float* __restrict__ b_hi,
    float* __restrict__ outp, int n, int nGrp, int Ep) {
    const int NS = 4;
    const int bid = blockIdx.x;
    const int xcd = bid & 7;
    const int half = xcd >> 2;
    const int grp = (bid >> 3) * 4 + (xcd & 3);
    if (grp >= nGrp) return;
    const int lane = threadIdx.x & 63;
    const int sub = lane >> 5;
    const int sl = lane & 31;
    const int wid0 = grp * 8 + (threadIdx.x >> 6) * 2 + sub;
    const bool ok = wid0 < n;
    const int wid = ok ? wid0 : (n - 1);
    const int col = half * 128 + sl * 4;
    const int slot = col >> 6;
    const float* __restrict__ wpl = wp + (size_t)slot * Ep;

    float e = as[(size_t)wid * NS + slot] + ad[(size_t)wid * NS + slot];
    e = fmaxf(e, 0.2f * e);
    float w = __expf(e);
    float denom = w;
    float4 hv = loadh4(h, (size_t)wid * 256 + col);
    float acc0 = w * hv.x, acc1 = w * hv.y, acc2 = w * hv.z, acc3 = w * hv.w;

    int rb = 0, re = 0;
    if (ok) { rb = rowptr[wid0]; re = rowptr[wid0 + 1]; }
    int p = rb;
    for (; p + 8 <= re; p += 8) {
        int4 sA = *(const int4*)(csr_src + p);
        int4 sB = *(const int4*)(csr_src + p + 4);
        float4 wA = *(const float4*)(wpl + p);
        float4 wB = *(const float4*)(wpl + p + 4);
        float4 h0 = loadh4(h, (size_t)sA.x * 256 + col);
        float4 h1 = loadh4(h, (size_t)sA.y * 256 + col);
        float4 h2 = loadh4(h, (size_t)sA.z * 256 + col);
        float4 h3 = loadh4(h, (size_t)sA.w * 256 + col);
        float4 h4 = loadh4(h, (size_t)sB.x * 256 + col);
        float4 h5 = loadh4(h, (size_t)sB.y * 256 + col);
        float4 h6 = loadh4(h, (size_t)sB.z * 256 + col);
        float4 h7 = loadh4(h, (size_t)sB.w * 256 + col);
        denom += (wA.x + wA.y + wA.z + wA.w) + (wB.x + wB.y + wB.z + wB.w);
        acc0 += wA.x * h0.x + wA.y * h1.x + wA.z * h2.x + wA.w * h3.x +
                wB.x * h4.x + wB.y * h5.x + wB.z * h6.x + wB.w * h7.x;
        acc1 += wA.x * h0.y + wA.y * h1.y + wA.z * h2.y + wA.w * h3.y +
                wB.x * h4.y + wB.y * h5.y + wB.z * h6.y + wB.w * h7.y;
        acc2 += wA.x * h0.z + wA.y * h1.z + wA.z * h2.z + wA.w * h3.z +
                wB.x * h4.z + wB.y * h5.z + wB.z * h6.z + wB.w * h7.z;
        acc3 += wA.x * h0.w + wA.y * h1.w + wA.z * h2.w + wA.w * h3.w +
                wB.x * h4.w + wB.y * h5.w + wB.z * h6.w + wB.w * h7.w;
    }
    for (; p + 4 <= re; p += 4) {
        int4 sA = *(const int4*)(csr_src + p);
        float4 wA = *(const float4*)(wpl + p);
        float4 h0 = loadh4(h, (size_t)sA.x * 256 + col);
        float4 h1 = loadh4(h, (size_t)sA.y * 256 + col);
        float4 h2 = loadh4(h, (size_t)sA.z * 256 + col);
        float4 h3 = loadh4(h, (size_t)sA.w * 256 + col);
        denom += (wA.x + wA.y) + (wA.z + wA.w);
        acc0 += wA.x * h0.x + wA.y * h1.x + wA.z * h2.x + wA.w * h3.x;
        acc1 += wA.x * h0.y + wA.y * h1.y + wA.z * h2.y + wA.w * h3.y;
        acc2 += wA.x * h0.z + wA.y * h1.z + wA.z * h2.z + wA.w * h3.z;
        acc3 += wA.x * h0.w + wA.y * h1.w + wA.z * h2.w + wA.w * h3.w;
    }
    for (; p < re; ++p) {
        int s = csr_src[p];
        float ww = wpl[p];
        float4 hh = loadh4(h, (size_t)s * 256 + col);
        denom += ww;
        acc0 += ww * hh.x;
        acc1 += ww * hh.y;
        acc2 += ww * hh.z;
        acc3 += ww * hh.w;
    }
    float inv = 1.0f / (denom + 1e-16f);

    const float* bp = half ? b_hi : b_lo;
    const int ci = sl * 4;
    float4 bv = *(const float4*)(bp + ci);
    float v0 = acc0 * inv + bv.x;
    float v1 = acc1 * inv + bv.y;
    float v2 = acc2 * inv + bv.z;
    float v3 = acc3 * inv + bv.w;

    if (!ok) return;
    size_t base = half ? ((size_t)n * 128 + (size_t)wid0 * 128 + ci)
                       : ((size_t)wid0 * 128 + ci);
    store4(outp, base, make_float4(v0, v1, v2, v3));
}

// ---------------------------------------------------------------------------
extern "C" void kernel_launch(void* const* d_in, const int* in_sizes, int n_in,
                              void* d_out, int out_size, void* d_ws, size_t ws_size,
                              hipStream_t stream) {
    const float* x = (const float*)d_in[0];
    const u32* ebuf = (const u32*)d_in[1];
    const float* W1 = (const float*)d_in[2];
    const float* a_src1 = (const float*)d_in[3];
    const float* a_dst1 = (const float*)d_in[4];
    const float* b1 = (const float*)d_in[5];
    const float* W_mu = (const float*)d_in[6];
    const float* a_src_mu = (const float*)d_in[7];
    const float* a_dst_mu = (const float*)d_in[8];
    const float* b_mu = (const float*)d_in[9];
    const float* W_ls = (const float*)d_in[10];
    const float* a_src_ls = (const float*)d_in[11];
    const float* a_dst_ls = (const float*)d_in[12];
    const float* b_ls = (const float*)d_in[13];

    const int n = in_sizes[0] / 128;  // 50000
    const int E = in_sizes[1] / 2;    // 800000
    const int Ep = E + 8;

    char* base = (char*)d_ws;
    size_t off = 0;
    auto alloc = [&](size_t b) -> char* {
        char* p = base + off;
        off = (off + b + 255) & ~(size_t)255;
        return p;
    };
    int* rowptr = (int*)alloc((size_t)(n + 1) * 4);
    int* cursor = (int*)alloc((size_t)n * 4);
    int* csr = (int*)alloc((size_t)Ep * 4);
    int* csrd = (int*)alloc((size_t)E * 4);
    int* bsum = (int*)alloc(256 * 4);
    int* se = (int*)alloc((size_t)E * 4);
    int* de = (int*)alloc((size_t)E * 4);
    float* as = (float*)alloc((size_t)n * 4 * 4);
    float* ad = (float*)alloc((size_t)n * 4 * 4);
    float* wp = (float*)alloc((size_t)Ep * 4 * 4);
    float* v1 = (float*)alloc(4 * 128 * 4);
    float* v2s = (float*)alloc(4 * 256 * 4);
    float* v2d = (float*)alloc(4 * 256 * 4);
    u16* W1t = (u16*)alloc(256 * 128 * 2);
    u16* Wt2 = (u16*)alloc(256 * 256 * 2);
    u16* x1h = (u16*)alloc((size_t)n * 256 * 2);  // x1 fp16 [n,256]
    u16* xh = x1h;                                // alias: xh [n,128] dead before x1h written
    u16* h = (u16*)alloc((size_t)n * 256 * 2);    // h2 fp16 [n,256]
    u16* aggx = h;                                // alias: agg1 [n,256] dead before h2 written

    const int nb = (n + 255) / 256;
    const int eg = (E + 255) / 256;
    const int gg = (n + 127) / 128;
    const int nGrp = (n + 7) / 8;
    const int aggGrid2 = 8 * ((nGrp + 3) / 4);

    // edge normalize + CSR build
    hipMemsetAsync(cursor, 0, (size_t)n * 4, stream);
    k_extract<<<eg, 256, 0, stream>>>(ebuf, E, se, de, cursor);
    k_scan_a<<<nb, 256, 0, stream>>>(cursor, n, bsum);
    k_scan_b<<<1, 256, 0, stream>>>(bsum, nb);
    k_scan_c<<<nb, 256, 0, stream>>>(cursor, n, bsum, rowptr, cursor, E);
    k_fill<<<eg, 256, 0, stream>>>(se, de, E, cursor, csr, csrd);

    // weights + v-vectors + xh/as/ad
    k_tw<<<(256 * 128 + 255) / 256, 256, 0, stream>>>(W1, W1, 256, 128, W1t);
    k_tw<<<(256 * 256 + 255) / 256, 256, 0, stream>>>(W_mu, W_ls, 128, 256, Wt2);
    k_vdots1<<<1, 128, 0, stream>>>(W1, a_src1, a_dst1, v1);
    k_vdots2<<<1, 256, 0, stream>>>(W_mu, W_ls, a_src_mu, a_dst_mu, a_src_ls,
                                    a_dst_ls, v2s, v2d);
    k_cvt_asad<<<(n + 3) / 4, 256, 0, stream>>>(x, v1, xh, as, ad, n);

    // Layer 1: weights -> aggregate x (256B/edge) -> x1 = ELU(agg@W1+b1)
    k_w<2><<<eg, 256, 0, stream>>>(csr, csrd, as, ad, wp, E, Ep);
    k_agg1<<<(n + 7) / 8, 256, 0, stream>>>(xh, rowptr, csr, wp, as, ad, aggx, n, Ep);
    k_gemm_x1<<<gg, 256, 0, stream>>>(aggx, W1t, x1h, as, ad, b1, v2s, v2d, n);

    // Layers mu/ls: weights -> h2 = x1@[Wmu|Wls] -> aggregate (R12 shape)
    k_w<4><<<eg, 256, 0, stream>>>(csr, csrd, as, ad, wp, E, Ep);
    k_gemm_h<<<gg, 256, 0, stream>>>(x1h, Wt2, h, n);
    k_agg4<<<aggGrid2, 256, 0, stream>>>(h, rowptr, csr, wp, as, ad, b_mu, b_ls,
                                         (float*)d_out, n, nGrp, Ep);
}